// Round 1
// baseline (530.535 us; speedup 1.0000x reference)
//
#include <hip/hip_runtime.h>
#include <stdint.h>

#define IN_F   2048
#define OUT_F  2048
#define NROWS  8192   // 4 * 2048

typedef __bf16 bf16x8 __attribute__((ext_vector_type(8)));
typedef float  f32x4  __attribute__((ext_vector_type(4)));

// ---------- helpers ----------

__device__ __forceinline__ unsigned short f2bf_rtne(float f) {
    unsigned int u = __float_as_uint(f);
    u += 0x7FFFu + ((u >> 16) & 1u);   // round-to-nearest-even on bf16 boundary
    return (unsigned short)(u >> 16);
}

__device__ __forceinline__ float softplusf(float v) {
    float a = fabsf(v);
    return fmaxf(v, 0.0f) + log1pf(__expf(-a));
}

// async global->LDS, 16B per lane; LDS dest is wave-uniform base + lane*16
__device__ __forceinline__ void gload_lds16(const void* g, void* l) {
    __builtin_amdgcn_global_load_lds(
        (const __attribute__((address_space(1))) unsigned int*)g,
        (__attribute__((address_space(3))) unsigned int*)l,
        16 /*bytes*/, 0 /*offset*/, 0 /*aux*/);
}

// ---------- prep: fp32 -> bf16 conversions into workspace ----------

__global__ __launch_bounds__(256)
void prep_x_kernel(const float* __restrict__ x, unsigned short* __restrict__ xb, int n) {
    int i = (blockIdx.x * 256 + threadIdx.x) * 4;
    if (i < n) {
        float4 v = *(const float4*)(x + i);
        ushort4 o;
        o.x = f2bf_rtne(v.x); o.y = f2bf_rtne(v.y);
        o.z = f2bf_rtne(v.z); o.w = f2bf_rtne(v.w);
        *(ushort4*)(xb + i) = o;
    }
}

__global__ __launch_bounds__(256)
void prep_w_kernel(const float* __restrict__ mu, const float* __restrict__ sg,
                   unsigned short* __restrict__ kh, unsigned short* __restrict__ mh, int n) {
    int i = (blockIdx.x * 256 + threadIdx.x) * 4;
    if (i < n) {
        float4 m = *(const float4*)(mu + i);
        float4 s = *(const float4*)(sg + i);
        ushort4 ko, mo;
        ko.x = f2bf_rtne(m.x * softplusf(s.x));
        ko.y = f2bf_rtne(m.y * softplusf(s.y));
        ko.z = f2bf_rtne(m.z * softplusf(s.z));
        ko.w = f2bf_rtne(m.w * softplusf(s.w));
        mo.x = f2bf_rtne(m.x); mo.y = f2bf_rtne(m.y);
        mo.z = f2bf_rtne(m.z); mo.w = f2bf_rtne(m.w);
        *(ushort4*)(kh + i) = ko;
        *(ushort4*)(mh + i) = mo;
    }
}

// ---------- fused double-GEMM ----------
// C-tile 128x128 per block, 256 threads = 4 waves, each wave owns a 64x64
// quadrant = 4x4 grid of 16x16x32 bf16 MFMAs. Two accumulator sets (scores,
// comp) share the A fragments. BK=32. Staging: global_load_lds dwordx4.

__global__ __launch_bounds__(256)
void gemm_fused_kernel(const unsigned short* __restrict__ xb,  // [8192][2048] bf16
                       const unsigned short* __restrict__ kh,  // [2048][2048] bf16 keys
                       const unsigned short* __restrict__ mh,  // [2048][2048] bf16 mu
                       const float* __restrict__ gate,         // [2048]
                       float* __restrict__ out0,               // masked  [8192][2048]
                       float* __restrict__ out1,               // scores  [8192][2048]
                       float* __restrict__ out2)               // masked  [8192][2048]
{
    // unpadded tiles: global_load_lds requires contiguous lane-order dest
    __shared__ __align__(16) unsigned short As[128 * 32];
    __shared__ __align__(16) unsigned short Ks[128 * 32];
    __shared__ __align__(16) unsigned short Ms[128 * 32];

    const int tid  = threadIdx.x;
    const int lane = tid & 63;
    const int wv   = tid >> 6;

    const int bm = blockIdx.x;   // 0..63 over N rows
    const int bo = blockIdx.y;   // 0..15 over output features

    const int wm = (wv >> 1) * 64;   // wave quadrant in C tile
    const int wn = (wv & 1) * 64;

    // staging: chunk c covers LDS bytes [c*1024, (c+1)*1024) = rows [c*16, c*16+16)
    // lane covers 16B: row = c*16 + lane/4, elem col = (lane&3)*8
    const int srow = lane >> 2;
    const int scol = (lane & 3) * 8;

    f32x4 accS[4][4];
    f32x4 accC[4][4];
#pragma unroll
    for (int i = 0; i < 4; i++)
#pragma unroll
        for (int j = 0; j < 4; j++) {
            accS[i][j] = (f32x4){0.f, 0.f, 0.f, 0.f};
            accC[i][j] = (f32x4){0.f, 0.f, 0.f, 0.f};
        }

    const unsigned short* xg = xb + (size_t)(bm * 128) * IN_F;
    const unsigned short* kg = kh + (size_t)(bo * 128) * IN_F;
    const unsigned short* mg = mh + (size_t)(bo * 128) * IN_F;

    // fragment read coords (A and B^T both read 8 contiguous k at one row)
    const int frow = lane & 15;
    const int fk   = (lane >> 4) * 8;

    for (int kt = 0; kt < IN_F; kt += 32) {
        __syncthreads();   // previous iter's fragment reads done before overwrite
#pragma unroll
        for (int j = 0; j < 2; j++) {
            const int c = wv * 2 + j;
            const int r = c * 16 + srow;
            const size_t goff = (size_t)r * IN_F + kt + scol;
            gload_lds16(xg + goff, &As[c * 512]);
            gload_lds16(kg + goff, &Ks[c * 512]);
            gload_lds16(mg + goff, &Ms[c * 512]);
        }
        __syncthreads();   // staging visible

        bf16x8 af[4], kf[4], mf[4];
#pragma unroll
        for (int i = 0; i < 4; i++) {
            af[i] = *(const bf16x8*)&As[(wm + i * 16 + frow) * 32 + fk];
            kf[i] = *(const bf16x8*)&Ks[(wn + i * 16 + frow) * 32 + fk];
            mf[i] = *(const bf16x8*)&Ms[(wn + i * 16 + frow) * 32 + fk];
        }
#pragma unroll
        for (int i = 0; i < 4; i++)
#pragma unroll
            for (int j = 0; j < 4; j++) {
                accS[i][j] = __builtin_amdgcn_mfma_f32_16x16x32_bf16(af[i], kf[j], accS[i][j], 0, 0, 0);
                accC[i][j] = __builtin_amdgcn_mfma_f32_16x16x32_bf16(af[i], mf[j], accC[i][j], 0, 0, 0);
            }
    }

    // epilogue: D[m = quad*4 + r][n = lane&15] per 16x16 tile
    const float inv_sqrt_d = 0.022097086912079608f;  // 1/sqrt(2048)
    const int quad = lane >> 4;
    const int col0 = lane & 15;
    const size_t row_base = (size_t)bm * 128 + wm;
    const int    col_base = bo * 128 + wn;

#pragma unroll
    for (int j = 0; j < 4; j++) {
        const int col = col_base + j * 16 + col0;
        const float g = gate[col];
#pragma unroll
        for (int i = 0; i < 4; i++) {
#pragma unroll
            for (int r = 0; r < 4; r++) {
                const size_t row = row_base + i * 16 + quad * 4 + r;
                const size_t idx = row * OUT_F + col;
                const float s = accS[i][j][r] * inv_sqrt_d;
                const float c = accC[i][j][r];
                float w = s - g;
                w = w > 0.f ? w : 0.f;
                const float m = c * w;
                out0[idx] = m;
                out1[idx] = s;
                out2[idx] = m;
            }
        }
    }
}

// ---------- launch ----------

extern "C" void kernel_launch(void* const* d_in, const int* in_sizes, int n_in,
                              void* d_out, int out_size, void* d_ws, size_t ws_size,
                              hipStream_t stream) {
    const float* x    = (const float*)d_in[0];   // [4,2048,2048]
    const float* mu   = (const float*)d_in[1];   // [2048,2048]
    const float* sg   = (const float*)d_in[2];   // [2048,2048]
    const float* gate = (const float*)d_in[3];   // [2048]

    float* out0 = (float*)d_out;                         // final_output
    float* out1 = out0 + (size_t)NROWS * OUT_F;          // scores
    float* out2 = out1 + (size_t)NROWS * OUT_F;          // masked_output

    // workspace layout (bf16): xb 33.55MB | kh 8.39MB | mh 8.39MB  (50.3MB total)
    unsigned short* xb = (unsigned short*)d_ws;
    unsigned short* kh = xb + (size_t)NROWS * IN_F;
    unsigned short* mh = kh + (size_t)OUT_F * IN_F;

    prep_x_kernel<<<(NROWS * IN_F) / (256 * 4), 256, 0, stream>>>(x, xb, NROWS * IN_F);
    prep_w_kernel<<<(OUT_F * IN_F) / (256 * 4), 256, 0, stream>>>(mu, sg, kh, mh, OUT_F * IN_F);

    dim3 grid(NROWS / 128, OUT_F / 128);  // 64 x 16
    gemm_fused_kernel<<<grid, 256, 0, stream>>>(xb, kh, mh, gate, out0, out1, out2);
}